// Round 10
// baseline (19.725 us; speedup 1.0000x reference)
//
#include <hip/hip_runtime.h>
#include <math.h>

// B=8, N=20, H=W=512. loss = sum(bce*valid)/cnt where the last point n with
// exp(-d2/(2*5^2)) > 0.1 (<=> d2 < 50*ln10) defines the per-pixel label.
// Single dispatch; 256 blocks x 512 threads (16 rows each); sleep-backed
// paired-flag handshake; zero-barrier single-wave finalize in block 0.

#define R2_THRESH 115.12925464970229f
#define HW 512
#define NPTS 20
#define NBLOCKS 256              // 8 batches * 32 chunks of 16 rows
#define NROWS 16
#define MAGIC 0x5F3C9A17u
#define MAGIC2 0x5F3C9A175F3C9A17ull

__global__ __launch_bounds__(512)
void pce_kernel(const float* __restrict__ y_pred,
                const int* __restrict__ point_labels,
                const float* __restrict__ point_coords,
                unsigned long long* __restrict__ slots, // [256] packed {C:hi32,S:lo32}
                unsigned* __restrict__ flags,           // [256]; != MAGIC on entry, cleared on exit
                float* __restrict__ out) {
    const int bid  = blockIdx.x;
    const int b    = bid >> 5;               // 32 chunks per batch
    const int y0   = (bid & 31) * NROWS;
    const int tid  = threadIdx.x;
    const int r    = tid >> 5;               // 16 rows, 32 lanes each
    const int lane = tid & 31;

    __shared__ float s_strip[NROWS][HW];     // 32 KB
    __shared__ float s_xc[NROWS][NPTS], s_lim[NROWS][NPTS], s_lab[NROWS][NPTS];

    // ---- issue strip loads first (independent of coords) ----
    const float4* grow = (const float4*)(y_pred + (size_t)b * HW * HW + (size_t)(y0 + r) * HW);
    float4 v0 = grow[lane];
    float4 v1 = grow[lane + 32];
    float4 v2 = grow[lane + 64];
    float4 v3 = grow[lane + 96];

    // ---- coords / tables / bbox (overlaps strip loads) ----
    float xlo = INFINITY, xhi = -INFINITY;
    if (lane < NPTS) {
        float2 cc = ((const float2*)point_coords)[b * NPTS + lane];
        float yc  = cc.x * (float)HW;
        float xc  = cc.y * (float)HW;
        float dy  = (float)(y0 + r) - yc;
        float lim = R2_THRESH - dy * dy;      // lim<=0 -> dx*dx<lim never true
        s_xc[r][lane]  = xc;
        s_lim[r][lane] = lim;
        s_lab[r][lane] = (float)point_labels[b * NPTS + lane];
        if (lim > 0.0f) {
            float s = sqrtf(lim);
            xlo = xc - s;
            xhi = xc + s;
        }
    }
    #pragma unroll
    for (int off = 16; off > 0; off >>= 1) {
        xlo = fminf(xlo, __shfl_xor(xlo, off, 32));
        xhi = fmaxf(xhi, __shfl_xor(xhi, off, 32));
    }
    const int x0 = (int)fminf(fmaxf(floorf(xlo), 0.0f), 512.0f);
    const int x1 = (int)fminf(fmaxf(ceilf(xhi), -1.0f), 511.0f);   // empty -> x0 > x1

    // ---- strip -> LDS ----
    {
        float4* dst = (float4*)&s_strip[r][0];
        dst[lane]      = v0;
        dst[lane + 32] = v1;
        dst[lane + 64] = v2;
        dst[lane + 96] = v3;
    }
    __syncthreads();

    // ---- pixel loop over this row's bbox (LDS reads) ----
    float sum = 0.0f, cnt = 0.0f;
    for (int px = x0 + lane; px <= x1; px += 32) {
        float l = s_strip[r][px];
        const float fx = (float)px;
        float lab = 0.0f;
        bool  valid = false;
        #pragma unroll
        for (int k = 0; k < NPTS; ++k) {
            float dx = fx - s_xc[r][k];
            if (dx * dx < s_lim[r][k]) { lab = s_lab[r][k]; valid = true; }  // last k wins
        }
        if (valid) {
            sum += fmaxf(l, 0.0f) - l * lab + log1pf(expf(-fabsf(l)));
            cnt += 1.0f;
        }
    }

    // ---- block reduction: 8 waves ----
    #pragma unroll
    for (int off = 32; off > 0; off >>= 1) {
        sum += __shfl_down(sum, off, 64);
        cnt += __shfl_down(cnt, off, 64);
    }
    __shared__ float rs[8], rc[8];
    if ((tid & 63) == 0) { rs[tid >> 6] = sum; rc[tid >> 6] = cnt; }
    __syncthreads();
    if (tid == 0) {
        float S = 0.0f, C = 0.0f;
        #pragma unroll
        for (int i = 0; i < 8; ++i) { S += rs[i]; C += rc[i]; }
        unsigned long long w = ((unsigned long long)__float_as_uint(C) << 32)
                             | (unsigned long long)__float_as_uint(S);
        __hip_atomic_store(&slots[bid], w, __ATOMIC_RELAXED, __HIP_MEMORY_SCOPE_AGENT);
        __hip_atomic_store(&flags[bid], MAGIC, __ATOMIC_RELEASE, __HIP_MEMORY_SCOPE_AGENT);
    }
    if (bid != 0 || tid >= 64) return;

    // ---- block 0, wave 0, zero barriers: lane t owns blocks 4t..4t+3 ----
    unsigned long long* fp = (unsigned long long*)&flags[4 * tid];
    {
        unsigned long long f0 = 0, f1 = 0;
        do {
            if (f0 != MAGIC2)
                f0 = __hip_atomic_load(&fp[0], __ATOMIC_ACQUIRE, __HIP_MEMORY_SCOPE_AGENT);
            if (f1 != MAGIC2)
                f1 = __hip_atomic_load(&fp[1], __ATOMIC_ACQUIRE, __HIP_MEMORY_SCOPE_AGENT);
            if (f0 != MAGIC2 || f1 != MAGIC2) __builtin_amdgcn_s_sleep(1);
        } while (f0 != MAGIC2 || f1 != MAGIC2);
    }
    float S = 0.0f, C = 0.0f;
    #pragma unroll
    for (int i = 0; i < 4; ++i) {   // same-thread acquire->relaxed: ordered
        unsigned long long w = __hip_atomic_load(&slots[4 * tid + i], __ATOMIC_RELAXED, __HIP_MEMORY_SCOPE_AGENT);
        S += __uint_as_float((unsigned)(w & 0xffffffffull));
        C += __uint_as_float((unsigned)(w >> 32));
    }
    #pragma unroll
    for (int off = 32; off > 0; off >>= 1) {
        S += __shfl_down(S, off, 64);
        C += __shfl_down(C, off, 64);
    }
    if (tid == 0) out[0] = (C > 0.0f) ? (S / C) : 0.0f;
    // clear my 4 flags for the next replay (my reads are done)
    __hip_atomic_store(&fp[0], 0ull, __ATOMIC_RELAXED, __HIP_MEMORY_SCOPE_AGENT);
    __hip_atomic_store(&fp[1], 0ull, __ATOMIC_RELAXED, __HIP_MEMORY_SCOPE_AGENT);
}

extern "C" void kernel_launch(void* const* d_in, const int* in_sizes, int n_in,
                              void* d_out, int out_size, void* d_ws, size_t ws_size,
                              hipStream_t stream) {
    const float* y_pred       = (const float*)d_in[0];   // (8,1,512,512) f32
    const int*   point_labels = (const int*)d_in[1];     // (8,20) i32
    const float* point_coords = (const float*)d_in[2];   // (8,20,2) f32
    float*       out          = (float*)d_out;           // scalar f32

    char* w = (char*)d_ws;
    unsigned long long* slots = (unsigned long long*)(w);      // 256 x 8B
    unsigned*           flags = (unsigned*)(w + 2048);         // 256 u32 (8B-aligned)

    pce_kernel<<<NBLOCKS, 512, 0, stream>>>(y_pred, point_labels, point_coords,
                                            slots, flags, out);
}